// Round 8
// baseline (126.046 us; speedup 1.0000x reference)
//
#include <hip/hip_runtime.h>
#include <hip/hip_bf16.h>

#define B_TOTAL 65536
#define NR 4
#define VD 100
#define HD 200
#define DK 32
#define MH 128
#define RD 64

typedef __attribute__((ext_vector_type(8))) short bf16x8;
typedef __attribute__((ext_vector_type(4))) float f32x4;
typedef __attribute__((ext_vector_type(8))) unsigned int u32x8;

static __device__ inline unsigned short f2bf(float x) {
    __hip_bfloat16 h = __float2bfloat16(x);
    return __builtin_bit_cast(unsigned short, h);
}

// ---- workspace layout (bytes) ---- total 953,344 B (< 1.02 MB proven in R1)
#define WS_GD    0         // 2400 * 8 = 19200
#define WS_CNT   19200     // 16
#define WS_LIST  19456     // 4 * 65536 * 2 = 524288 (ushort b per bucket slot)
#define WS_VB    543744    // 65536 bytes (v bit per element)
#define WS_W1F   609280    // 114688 * 2 = 229376
#define WS_W2F   838656    // 57344 * 2 = 114688

// ---------------- kernel 0a: precompute G (fp64) + zero counters ----------------
__global__ __launch_bounds__(256) void k0_prep(
    const float* __restrict__ rule_emb, const float* __restrict__ Wq,
    const float* __restrict__ bq, const float* __restrict__ Wk,
    double* __restrict__ Gd, int* __restrict__ cnt)
{
    int tid = threadIdx.x;
    if (tid < NR) cnt[tid] = 0;

    __shared__ double readS[NR * DK];
    if (tid < NR * DK) {
        int r = tid >> 5, k = tid & 31;
        double a = (double)bq[k];
        for (int d = 0; d < RD; ++d)
            a += (double)rule_emb[r * RD + d] * (double)Wq[d * DK + k];
        readS[tid] = a;
    }
    __syncthreads();

    for (int idx = tid; idx < 300 * 8; idx += 256) {
        int j = idx >> 3, p = idx & 7;
        int r = p >> 1, v = p & 1;
        int s = j / 100, dd = j - s * 100;
        double g = 0.0;
        if (s == v) {
            for (int k = 0; k < DK; ++k)
                g += (double)Wk[(v * HD + dd) * DK + k] * readS[r * DK + k];
        } else if (s == 2) {
            for (int k = 0; k < DK; ++k)
                g += (double)Wk[(v * HD + 100 + dd) * DK + k] * readS[r * DK + k];
        }
        Gd[idx] = g;  // layout Gd[j*8 + p]
    }
}

// ---------------- kernel 0b: W1/W2 -> bf16 MFMA B-fragment layout ----------------
__global__ __launch_bounds__(256) void k0_wfrag(
    const float* __restrict__ W1, const float* __restrict__ W2,
    unsigned short* __restrict__ W1f, unsigned short* __restrict__ W2f)
{
    int i = blockIdx.x * 256 + threadIdx.x;
    if (i < 114688) {
        int r = i / 28672, rem = i % 28672;
        int ks = rem / 4096, rem2 = rem % 4096;
        int n = rem2 >> 9, l = (rem2 >> 3) & 63, j = rem2 & 7;
        int k = ks * 32 + ((l >> 4) << 3) + j;
        int c = n * 16 + (l & 15);
        float v = (k < HD) ? W1[((size_t)r * HD + k) * MH + c] : 0.f;
        W1f[i] = f2bf(v);
    } else if (i < 114688 + 57344) {
        int t = i - 114688;
        int r = t / 14336, rem = t % 14336;
        int ks = rem / 3584, rem2 = rem % 3584;
        int n = rem2 >> 9, l = (rem2 >> 3) & 63, j = rem2 & 7;
        int k = ks * 32 + ((l >> 4) << 3) + j;
        int c = n * 16 + (l & 15);
        float v = (c < VD) ? W2[((size_t)r * MH + k) * VD + c] : 0.f;
        W2f[t] = f2bf(v);
    }
}

// ---------------- kernel 1: selection (fp64) + bucket compaction ----------------
// v4: v3's structure (1 thread/row, 15-deep batched hidden loads), but G is
// read via EXPLICIT inline-asm s_load_dwordx8 pairs (K$-cached, scalar pipe).
// Evidence: R7's k1 ~42us matches 2400 per-lane VMEM issues/thread (the
// compiler did not scalarize the wave-uniform G loads on its own). Forcing
// SMEM drops per-thread VMEM issues 2400->75. Same G bits, same fp64 fma
// order -> bit-identical scores -> identical argmax to R5/R7 (proven).
__global__ __launch_bounds__(256) void k1_select(
    const float* __restrict__ hidden, const double* __restrict__ Gd,
    int* __restrict__ cnt, unsigned short* __restrict__ list16,
    unsigned char* __restrict__ vbyte)
{
    __shared__ int lcnt[NR];
    __shared__ int lbase[NR];
    int tid = threadIdx.x;
    if (tid < NR) lcnt[tid] = 0;
    __syncthreads();

    int b = blockIdx.x * 256 + tid;
    const float4* h4 = (const float4*)(hidden + (size_t)b * 300);

    double acc[8];
#pragma unroll
    for (int p = 0; p < 8; ++p) acc[p] = 0.0;

    for (int c0 = 0; c0 < 75; c0 += 15) {
        float4 hv[15];
#pragma unroll
        for (int u = 0; u < 15; ++u) hv[u] = h4[c0 + u];
#pragma unroll
        for (int u = 0; u < 15; ++u) {
            float he[4] = {hv[u].x, hv[u].y, hv[u].z, hv[u].w};
            int j0 = (c0 + u) * 4;
#pragma unroll
            for (int q = 0; q < 4; ++q) {
                double x = (double)he[q];
                // scalar load of G[j][0..8): 64 B at byte offset j*64
                unsigned off0 = __builtin_amdgcn_readfirstlane((j0 + q) * 64);
                unsigned off1 = off0 + 32;
                u32x8 ga, gb;
                asm volatile(
                    "s_load_dwordx8 %0, %2, %3\n\t"
                    "s_load_dwordx8 %1, %2, %4\n\t"
                    "s_waitcnt lgkmcnt(0)"
                    : "=&s"(ga), "=&s"(gb)
                    : "s"(Gd), "s"(off0), "s"(off1));
                double gg[8];
                __builtin_memcpy(&gg[0], &ga, 32);
                __builtin_memcpy(&gg[4], &gb, 32);
#pragma unroll
                for (int p = 0; p < 8; ++p) acc[p] = fma(x, gg[p], acc[p]);
            }
        }
    }

    // first-occurrence argmax (matches jnp.argmax)
    int best = 0; double bv = acc[0];
#pragma unroll
    for (int p = 1; p < 8; ++p) if (acc[p] > bv) { bv = acc[p]; best = p; }
    int r = best >> 1, v = best & 1;

    vbyte[b] = (unsigned char)v;
    int pos = atomicAdd(&lcnt[r], 1);
    __syncthreads();
    if (tid < NR) lbase[tid] = atomicAdd(&cnt[tid], lcnt[tid]);
    __syncthreads();
    list16[r * B_TOTAL + lbase[r] + pos] = (unsigned short)b;
}

// ---------------- kernel 2: bucketed bf16-MFMA MLP ----------------
// v2 staging: 2 threads/row, each batch-loads its 25 CONSECUTIVE float4
// (one 400B segment) into registers before convert+LDS-store. R7 counters
// (MfmaUtil 4%, VALUBusy 8%, dur 46us >> 2.2us MFMA work) showed the
// gather staging was a 25-deep serialized load->convert->store chain.
// GEMMs and layouts unchanged (proven).
__global__ __launch_bounds__(256) void k2_mlp(
    const float* __restrict__ hidden,
    const unsigned short* __restrict__ W1f, const unsigned short* __restrict__ W2f,
    const int* __restrict__ cnt, const unsigned short* __restrict__ list16,
    const unsigned char* __restrict__ vbyte, float* __restrict__ out)
{
    int r = blockIdx.y;
    int nb = cnt[r];
    int m0 = blockIdx.x * 128;
    if (m0 >= nb) return;
    int me = nb - m0; if (me > 128) me = 128;

    __shared__ __align__(16) unsigned short shbuf[128 * 232]; // X: [128][232] ; later C1: [128][136]
    __shared__ int ent[128];

    int tid = threadIdx.x;
    int wave = tid >> 6, lane = tid & 63;
    int lr = lane & 15, lk = lane >> 4;
    int wrow0 = wave * 32;

    if (tid < 128) {
        int idx = m0 + tid; if (idx > nb - 1) idx = nb - 1;
        int b = list16[r * B_TOTAL + idx];
        int v = vbyte[b];
        ent[tid] = (b << 1) | v;
    }
    __syncthreads();

    // stage X (bf16): thread pair (e,half): half 0 -> seg v, half 1 -> seg 1-v;
    // 25 consecutive float4 batched into regs (deep ILP), then convert+store.
    {
        int e = tid >> 1, half = tid & 1;
        int en = ent[e];
        int b = en >> 1, v = en & 1;
        int seg = half ? (1 - v) : v;
        const float4* src = (const float4*)(hidden + (size_t)b * 300 + seg * 100);
        float4 hv[25];
#pragma unroll
        for (int u = 0; u < 25; ++u) hv[u] = src[u];
        int qbase = half * 25;
#pragma unroll
        for (int u = 0; u < 25; ++u) {
            ushort4 o;
            o.x = f2bf(hv[u].x); o.y = f2bf(hv[u].y);
            o.z = f2bf(hv[u].z); o.w = f2bf(hv[u].w);
            *(ushort4*)&shbuf[e * 232 + (qbase + u) * 4] = o;
        }
    }
    // zero-pad k = [200,232) COMPLETELY: 4 bf16x8 chunks/row.
    // (GEMM1 ks=6 reads k in [192,224): any stale LDS NaN * 0-weight = NaN
    //  poisons the C1 row, relu launders NaN->0 -> zeroed output rows.)
    for (int i = tid; i < 128 * 4; i += 256) {
        int row = i >> 2, part = i & 3;
        bf16x8 z = {0, 0, 0, 0, 0, 0, 0, 0};
        *(bf16x8*)&shbuf[row * 232 + 200 + part * 8] = z;
    }
    __syncthreads();

    // ---- GEMM1 ----
    const unsigned short* W1f_r = W1f + (size_t)r * 28672;
    f32x4 acc1[2][8];
#pragma unroll
    for (int mt = 0; mt < 2; ++mt)
#pragma unroll
        for (int n = 0; n < 8; ++n) acc1[mt][n] = (f32x4){0.f, 0.f, 0.f, 0.f};

#pragma unroll
    for (int ks = 0; ks < 7; ++ks) {
        bf16x8 a0 = *(const bf16x8*)&shbuf[(wrow0 + lr) * 232 + ks * 32 + lk * 8];
        bf16x8 a1 = *(const bf16x8*)&shbuf[(wrow0 + 16 + lr) * 232 + ks * 32 + lk * 8];
#pragma unroll
        for (int n = 0; n < 8; ++n) {
            bf16x8 bfr = *(const bf16x8*)&W1f_r[(size_t)(ks * 8 + n) * 512 + lane * 8];
            acc1[0][n] = __builtin_amdgcn_mfma_f32_16x16x32_bf16(a0, bfr, acc1[0][n], 0, 0, 0);
            acc1[1][n] = __builtin_amdgcn_mfma_f32_16x16x32_bf16(a1, bfr, acc1[1][n], 0, 0, 0);
        }
    }

    __syncthreads();  // all waves done reading X before overlay

    // relu -> bf16 -> C1 transpose-store via C-layout: row=(lane>>4)*4+j, col=n*16+(lane&15)
#pragma unroll
    for (int mt = 0; mt < 2; ++mt)
#pragma unroll
        for (int n = 0; n < 8; ++n)
#pragma unroll
            for (int j = 0; j < 4; ++j) {
                float v = fmaxf(acc1[mt][n][j], 0.f);
                int row = wrow0 + mt * 16 + lk * 4 + j;
                shbuf[row * 136 + n * 16 + lr] = f2bf(v);
            }
    __syncthreads();

    // ---- GEMM2 ----
    const unsigned short* W2f_r = W2f + (size_t)r * 14336;
    f32x4 acc2[2][7];
#pragma unroll
    for (int mt = 0; mt < 2; ++mt)
#pragma unroll
        for (int n = 0; n < 7; ++n) acc2[mt][n] = (f32x4){0.f, 0.f, 0.f, 0.f};

#pragma unroll
    for (int ks = 0; ks < 4; ++ks) {
        bf16x8 a0 = *(const bf16x8*)&shbuf[(wrow0 + lr) * 136 + ks * 32 + lk * 8];
        bf16x8 a1 = *(const bf16x8*)&shbuf[(wrow0 + 16 + lr) * 136 + ks * 32 + lk * 8];
#pragma unroll
        for (int n = 0; n < 7; ++n) {
            bf16x8 bfr = *(const bf16x8*)&W2f_r[(size_t)(ks * 7 + n) * 512 + lane * 8];
            acc2[0][n] = __builtin_amdgcn_mfma_f32_16x16x32_bf16(a0, bfr, acc2[0][n], 0, 0, 0);
            acc2[1][n] = __builtin_amdgcn_mfma_f32_16x16x32_bf16(a1, bfr, acc2[1][n], 0, 0, 0);
        }
    }

    // scatter-store
#pragma unroll
    for (int mt = 0; mt < 2; ++mt)
#pragma unroll
        for (int n = 0; n < 7; ++n) {
            int col = n * 16 + lr;
            if (col < VD) {
#pragma unroll
                for (int j = 0; j < 4; ++j) {
                    int e = wrow0 + mt * 16 + lk * 4 + j;
                    if (e < me) {
                        int b = ent[e] >> 1;
                        out[(size_t)b * VD + col] = acc2[mt][n][j];
                    }
                }
            }
        }
}

extern "C" void kernel_launch(void* const* d_in, const int* in_sizes, int n_in,
                              void* d_out, int out_size, void* d_ws, size_t ws_size,
                              hipStream_t stream) {
    (void)in_sizes; (void)n_in; (void)out_size; (void)ws_size;
    const float* hidden   = (const float*)d_in[0];
    const float* rule_emb = (const float*)d_in[1];
    const float* Wq       = (const float*)d_in[2];
    const float* bq       = (const float*)d_in[3];
    const float* Wk       = (const float*)d_in[4];
    const float* W1       = (const float*)d_in[5];
    const float* W2       = (const float*)d_in[6];
    float* out = (float*)d_out;

    char* ws = (char*)d_ws;
    double* Gd            = (double*)(ws + WS_GD);
    int* cnt              = (int*)(ws + WS_CNT);
    unsigned short* list16 = (unsigned short*)(ws + WS_LIST);
    unsigned char* vbyte  = (unsigned char*)(ws + WS_VB);
    unsigned short* W1f   = (unsigned short*)(ws + WS_W1F);
    unsigned short* W2f   = (unsigned short*)(ws + WS_W2F);

    k0_prep<<<1, 256, 0, stream>>>(rule_emb, Wq, bq, Wk, Gd, cnt);
    k0_wfrag<<<672, 256, 0, stream>>>(W1, W2, W1f, W2f);
    k1_select<<<256, 256, 0, stream>>>(hidden, Gd, cnt, list16, vbyte);
    k2_mlp<<<dim3(512, NR), 256, 0, stream>>>(hidden, W1f, W2f, cnt, list16, vbyte, out);
}

// Round 9
// 84.698 us; speedup vs baseline: 1.4882x; 1.4882x over previous
//
#include <hip/hip_runtime.h>
#include <hip/hip_bf16.h>

#define B_TOTAL 65536
#define NR 4
#define VD 100
#define HD 200
#define DK 32
#define MH 128
#define RD 64

typedef __attribute__((ext_vector_type(8))) short bf16x8;
typedef __attribute__((ext_vector_type(4))) float f32x4;

static __device__ inline unsigned short f2bf(float x) {
    __hip_bfloat16 h = __float2bfloat16(x);
    return __builtin_bit_cast(unsigned short, h);
}

// ---- workspace layout (bytes) ----
#define WS_GC    0         // 1600 * 8 = 12800 (packed G, block-sparse form)
#define WS_CNT   19200     // 16
#define WS_LIST  19456     // 4 * 65536 * 2 = 524288
#define WS_VB    543744    // 65536
#define WS_W1F   609280    // 229376
#define WS_W2F   838656    // 114688

// ---------------- kernel 0a: packed G (fp64) + zero counters ----------------
// G is block-sparse: score(r,v) = dot(h[v], A[v][r]) + dot(h[2], B[v][r]).
// Gc[dd][c], c=0..15: c=v*4+r -> A[v][r][dd]; c=8+v*4+r -> B[v][r][dd].
// K per score: 200 (was 300 with explicit zeros).
__global__ __launch_bounds__(256) void k0_prep(
    const float* __restrict__ rule_emb, const float* __restrict__ Wq,
    const float* __restrict__ bq, const float* __restrict__ Wk,
    double* __restrict__ Gc, int* __restrict__ cnt)
{
    int tid = threadIdx.x;
    if (tid < NR) cnt[tid] = 0;

    __shared__ double readS[NR * DK];
    if (tid < NR * DK) {
        int r = tid >> 5, k = tid & 31;
        double a = (double)bq[k];
        for (int d = 0; d < RD; ++d)
            a += (double)rule_emb[r * RD + d] * (double)Wq[d * DK + k];
        readS[tid] = a;
    }
    __syncthreads();

    for (int idx = tid; idx < 100 * 16; idx += 256) {
        int dd = idx >> 4, c = idx & 15;
        int isB = (c >> 3) & 1, v = (c >> 2) & 1, r = c & 3;
        int row = v * HD + isB * 100 + dd;
        double g = 0.0;
        for (int k = 0; k < DK; ++k)
            g += (double)Wk[row * DK + k] * readS[r * DK + k];
        Gc[idx] = g;   // layout Gc[dd*16 + c]
    }
}

// ---------------- kernel 0b: W1/W2 -> bf16 MFMA B-fragment layout ----------------
__global__ __launch_bounds__(256) void k0_wfrag(
    const float* __restrict__ W1, const float* __restrict__ W2,
    unsigned short* __restrict__ W1f, unsigned short* __restrict__ W2f)
{
    int i = blockIdx.x * 256 + threadIdx.x;
    if (i < 114688) {
        int r = i / 28672, rem = i % 28672;
        int ks = rem / 4096, rem2 = rem % 4096;
        int n = rem2 >> 9, l = (rem2 >> 3) & 63, j = rem2 & 7;
        int k = ks * 32 + ((l >> 4) << 3) + j;
        int c = n * 16 + (l & 15);
        float v = (k < HD) ? W1[((size_t)r * HD + k) * MH + c] : 0.f;
        W1f[i] = f2bf(v);
    } else if (i < 114688 + 57344) {
        int t = i - 114688;
        int r = t / 14336, rem = t % 14336;
        int ks = rem / 3584, rem2 = rem % 3584;
        int n = rem2 >> 9, l = (rem2 >> 3) & 63, j = rem2 & 7;
        int k = ks * 32 + ((l >> 4) << 3) + j;
        int c = n * 16 + (l & 15);
        float v = (c < VD) ? W2[((size_t)r * MH + k) * VD + c] : 0.f;
        W2f[t] = f2bf(v);
    }
}

// ---------------- kernel 1: selection (fp64) + bucket compaction ----------------
// v5: block-sparse packed G in LDS [100][16] fp64 (12.8 KB, uniform-address
// broadcast, compiler-mergeable ds_read_b128), 1600 FMA/row (was 2400),
// h loaded 15-float4-deep per 20-dd chunk. Fully unrolled body -> compiler
// hoists/pipelines LDS reads (no inline asm: R8 proved per-iter asm
// s_load+lgkmcnt(0) serializes, 42->78us). fp64 partial-sum reorder only
// perturbs ~1e-16 relative; argmax safe (needs ~1e-13 gap to flip).
__global__ __launch_bounds__(256) void k1_select(
    const float* __restrict__ hidden, const double* __restrict__ Gc,
    int* __restrict__ cnt, unsigned short* __restrict__ list16,
    unsigned char* __restrict__ vbyte)
{
    __shared__ double Gs[100 * 16];   // 12800 B
    __shared__ int lcnt[NR];
    __shared__ int lbase[NR];
    int tid = threadIdx.x;
    for (int i = tid; i < 1600; i += 256) Gs[i] = Gc[i];
    if (tid < NR) lcnt[tid] = 0;
    __syncthreads();

    int b = blockIdx.x * 256 + tid;
    const float4* h0 = (const float4*)(hidden + (size_t)b * 300);  // seg s=0
    const float4* h1 = h0 + 25;                                    // seg s=1
    const float4* h2 = h0 + 50;                                    // seg s=2

    double acc[16];
#pragma unroll
    for (int c = 0; c < 16; ++c) acc[c] = 0.0;

    for (int t0 = 0; t0 < 25; t0 += 5) {
        float4 va[5], vb[5], vc[5];
#pragma unroll
        for (int u = 0; u < 5; ++u) { va[u] = h0[t0 + u]; vb[u] = h1[t0 + u]; vc[u] = h2[t0 + u]; }
#pragma unroll
        for (int u = 0; u < 5; ++u) {
            float e0[4] = {va[u].x, va[u].y, va[u].z, va[u].w};
            float e1[4] = {vb[u].x, vb[u].y, vb[u].z, vb[u].w};
            float e2[4] = {vc[u].x, vc[u].y, vc[u].z, vc[u].w};
#pragma unroll
            for (int q = 0; q < 4; ++q) {
                int dd = (t0 + u) * 4 + q;
                const double* g = &Gs[dd * 16];
                double x0 = (double)e0[q], x1 = (double)e1[q], x2 = (double)e2[q];
#pragma unroll
                for (int r = 0; r < 4; ++r) acc[r]     = fma(x0, g[r],     acc[r]);
#pragma unroll
                for (int r = 0; r < 4; ++r) acc[4 + r] = fma(x1, g[4 + r], acc[4 + r]);
#pragma unroll
                for (int r = 0; r < 8; ++r) acc[8 + r] = fma(x2, g[8 + r], acc[8 + r]);
            }
        }
    }

    // scores p = r*2+v (reshape order); first-occurrence argmax
    double sc[8];
#pragma unroll
    for (int r = 0; r < 4; ++r) {
        sc[r * 2]     = acc[r]     + acc[8 + r];
        sc[r * 2 + 1] = acc[4 + r] + acc[12 + r];
    }
    int best = 0; double bv = sc[0];
#pragma unroll
    for (int p = 1; p < 8; ++p) if (sc[p] > bv) { bv = sc[p]; best = p; }
    int r = best >> 1, v = best & 1;

    vbyte[b] = (unsigned char)v;
    int pos = atomicAdd(&lcnt[r], 1);
    __syncthreads();
    if (tid < NR) lbase[tid] = atomicAdd(&cnt[tid], lcnt[tid]);
    __syncthreads();
    list16[r * B_TOTAL + lbase[r] + pos] = (unsigned short)b;
}

// ---------------- kernel 2: bucketed bf16-MFMA MLP ----------------
// v3: 64-row tiles (LDS 30KB -> ~5 blocks/CU, occupancy 10%->~40% to hide
// staging+LDS latency via block overlap; R7 showed each 128-row block ran
// ~alone per CU, fully latency-exposed). 4 threads/row staging, 13 batched
// float4 each (deep ILP, benign duplicate write at chunk 12). Per wave:
// 16 rows, GEMM1 7ks x 8n = 56 MFMA, GEMM2 4ks x 7n = 28 MFMA.
__global__ __launch_bounds__(256) void k2_mlp(
    const float* __restrict__ hidden,
    const unsigned short* __restrict__ W1f, const unsigned short* __restrict__ W2f,
    const int* __restrict__ cnt, const unsigned short* __restrict__ list16,
    const unsigned char* __restrict__ vbyte, float* __restrict__ out)
{
    int r = blockIdx.y;
    int nb = cnt[r];
    int m0 = blockIdx.x * 64;
    if (m0 >= nb) return;
    int me = nb - m0; if (me > 64) me = 64;

    __shared__ __align__(16) unsigned short shbuf[64 * 232]; // X [64][232]; C1 overlay [64][136]
    __shared__ int ent[64];

    int tid = threadIdx.x;
    int wave = tid >> 6, lane = tid & 63;
    int lr = lane & 15, lk = lane >> 4;
    int wrow0 = wave * 16;

    if (tid < 64) {
        int idx = m0 + tid; if (idx > nb - 1) idx = nb - 1;
        int b = list16[r * B_TOTAL + idx];
        int v = vbyte[b];
        ent[tid] = (b << 1) | v;
    }
    __syncthreads();

    // stage X: thread = (e, h, t): e=tid>>2 row, h=(tid>>1)&1 seg-half,
    // t=tid&1 sub-half. 13 consecutive float4 batched into regs.
    {
        int e = tid >> 2, hh = (tid >> 1) & 1, t = tid & 1;
        int en = ent[e];
        int b = en >> 1, v = en & 1;
        int seg = hh ? (1 - v) : v;
        int q0 = t * 12;   // 0..12 / 12..24 (chunk 12 written twice, same value)
        const float4* src = (const float4*)(hidden + (size_t)b * 300 + seg * 100) + q0;
        float4 hv[13];
#pragma unroll
        for (int u = 0; u < 13; ++u) hv[u] = src[u];
#pragma unroll
        for (int u = 0; u < 13; ++u) {
            ushort4 o;
            o.x = f2bf(hv[u].x); o.y = f2bf(hv[u].y);
            o.z = f2bf(hv[u].z); o.w = f2bf(hv[u].w);
            *(ushort4*)&shbuf[e * 232 + (hh * 25 + q0 + u) * 4] = o;
        }
    }
    // zero-pad k = [200,232) fully: 4 bf16x8 chunks per row (NaN-laundering
    // hazard: stale LDS * 0-weight = NaN -> relu -> zeroed rows).
    {
        int row = tid >> 2, part = tid & 3;
        bf16x8 z = {0, 0, 0, 0, 0, 0, 0, 0};
        *(bf16x8*)&shbuf[row * 232 + 200 + part * 8] = z;
    }
    __syncthreads();

    // ---- GEMM1 ----
    const unsigned short* W1f_r = W1f + (size_t)r * 28672;
    f32x4 acc1[8];
#pragma unroll
    for (int n = 0; n < 8; ++n) acc1[n] = (f32x4){0.f, 0.f, 0.f, 0.f};

#pragma unroll
    for (int ks = 0; ks < 7; ++ks) {
        bf16x8 a0 = *(const bf16x8*)&shbuf[(wrow0 + lr) * 232 + ks * 32 + lk * 8];
#pragma unroll
        for (int n = 0; n < 8; ++n) {
            bf16x8 bfr = *(const bf16x8*)&W1f_r[(size_t)(ks * 8 + n) * 512 + lane * 8];
            acc1[n] = __builtin_amdgcn_mfma_f32_16x16x32_bf16(a0, bfr, acc1[n], 0, 0, 0);
        }
    }

    __syncthreads();  // all waves done reading X before overlay

    // relu -> bf16 -> C1 transpose-store: row=wrow0+(lane>>4)*4+j, col=n*16+(lane&15)
#pragma unroll
    for (int n = 0; n < 8; ++n)
#pragma unroll
        for (int j = 0; j < 4; ++j) {
            float v = fmaxf(acc1[n][j], 0.f);
            int row = wrow0 + lk * 4 + j;
            shbuf[row * 136 + n * 16 + lr] = f2bf(v);
        }
    __syncthreads();

    // ---- GEMM2 ----
    const unsigned short* W2f_r = W2f + (size_t)r * 14336;
    f32x4 acc2[7];
#pragma unroll
    for (int n = 0; n < 7; ++n) acc2[n] = (f32x4){0.f, 0.f, 0.f, 0.f};

#pragma unroll
    for (int ks = 0; ks < 4; ++ks) {
        bf16x8 a0 = *(const bf16x8*)&shbuf[(wrow0 + lr) * 136 + ks * 32 + lk * 8];
#pragma unroll
        for (int n = 0; n < 7; ++n) {
            bf16x8 bfr = *(const bf16x8*)&W2f_r[(size_t)(ks * 7 + n) * 512 + lane * 8];
            acc2[n] = __builtin_amdgcn_mfma_f32_16x16x32_bf16(a0, bfr, acc2[n], 0, 0, 0);
        }
    }

    // scatter-store
#pragma unroll
    for (int n = 0; n < 7; ++n) {
        int col = n * 16 + lr;
        if (col < VD) {
#pragma unroll
            for (int j = 0; j < 4; ++j) {
                int e = wrow0 + lk * 4 + j;
                if (e < me) {
                    int b = ent[e] >> 1;
                    out[(size_t)b * VD + col] = acc2[n][j];
                }
            }
        }
    }
}

extern "C" void kernel_launch(void* const* d_in, const int* in_sizes, int n_in,
                              void* d_out, int out_size, void* d_ws, size_t ws_size,
                              hipStream_t stream) {
    (void)in_sizes; (void)n_in; (void)out_size; (void)ws_size;
    const float* hidden   = (const float*)d_in[0];
    const float* rule_emb = (const float*)d_in[1];
    const float* Wq       = (const float*)d_in[2];
    const float* bq       = (const float*)d_in[3];
    const float* Wk       = (const float*)d_in[4];
    const float* W1       = (const float*)d_in[5];
    const float* W2       = (const float*)d_in[6];
    float* out = (float*)d_out;

    char* ws = (char*)d_ws;
    double* Gc             = (double*)(ws + WS_GC);
    int* cnt               = (int*)(ws + WS_CNT);
    unsigned short* list16 = (unsigned short*)(ws + WS_LIST);
    unsigned char* vbyte   = (unsigned char*)(ws + WS_VB);
    unsigned short* W1f    = (unsigned short*)(ws + WS_W1F);
    unsigned short* W2f    = (unsigned short*)(ws + WS_W2F);

    k0_prep<<<1, 256, 0, stream>>>(rule_emb, Wq, bq, Wk, Gc, cnt);
    k0_wfrag<<<672, 256, 0, stream>>>(W1, W2, W1f, W2f);
    k1_select<<<256, 256, 0, stream>>>(hidden, Gc, cnt, list16, vbyte);
    k2_mlp<<<dim3(1024, NR), 256, 0, stream>>>(hidden, W1f, W2f, cnt, list16, vbyte, out);
}

// Round 10
// 71.529 us; speedup vs baseline: 1.7622x; 1.1841x over previous
//
#include <hip/hip_runtime.h>
#include <hip/hip_bf16.h>

#define B_TOTAL 65536
#define NR 4
#define VD 100
#define HD 200
#define DK 32
#define MH 128
#define RD 64

typedef __attribute__((ext_vector_type(8))) short bf16x8;
typedef __attribute__((ext_vector_type(4))) float f32x4;
// constant address space pointer -> compiler emits s_load (scalar K$ path)
typedef const double __attribute__((address_space(4)))* gconst_t;

static __device__ inline unsigned short f2bf(float x) {
    __hip_bfloat16 h = __float2bfloat16(x);
    return __builtin_bit_cast(unsigned short, h);
}

// ---- workspace layout (bytes) ----
#define WS_GC    0         // 1600 * 8 = 12800 (packed G, block-sparse form)
#define WS_CNT   19200     // 16
#define WS_LIST  19456     // 4 * 65536 * 2 = 524288
#define WS_VB    543744    // 65536
#define WS_W1F   609280    // 229376
#define WS_W2F   838656    // 114688

// ---------------- kernel 0a: packed G (fp64) + zero counters ----------------
// score(r,v) = dot(h[v], A[v][r]) + dot(h[2], B[v][r]).
// Gc[dd][c]: c = isB*8 + v*4 + r ; A at c<8, B at c>=8. K per score: 200.
__global__ __launch_bounds__(256) void k0_prep(
    const float* __restrict__ rule_emb, const float* __restrict__ Wq,
    const float* __restrict__ bq, const float* __restrict__ Wk,
    double* __restrict__ Gc, int* __restrict__ cnt)
{
    int tid = threadIdx.x;
    if (tid < NR) cnt[tid] = 0;

    __shared__ double readS[NR * DK];
    if (tid < NR * DK) {
        int r = tid >> 5, k = tid & 31;
        double a = (double)bq[k];
        for (int d = 0; d < RD; ++d)
            a += (double)rule_emb[r * RD + d] * (double)Wq[d * DK + k];
        readS[tid] = a;
    }
    __syncthreads();

    for (int idx = tid; idx < 100 * 16; idx += 256) {
        int dd = idx >> 4, c = idx & 15;
        int isB = (c >> 3) & 1, v = (c >> 2) & 1, r = c & 3;
        int row = v * HD + isB * 100 + dd;
        double g = 0.0;
        for (int k = 0; k < DK; ++k)
            g += (double)Wk[row * DK + k] * readS[r * DK + k];
        Gc[idx] = g;   // layout Gc[dd*16 + c]
    }
}

// ---------------- kernel 0b: W1/W2 -> bf16 MFMA B-fragment layout ----------------
__global__ __launch_bounds__(256) void k0_wfrag(
    const float* __restrict__ W1, const float* __restrict__ W2,
    unsigned short* __restrict__ W1f, unsigned short* __restrict__ W2f)
{
    int i = blockIdx.x * 256 + threadIdx.x;
    if (i < 114688) {
        int r = i / 28672, rem = i % 28672;
        int ks = rem / 4096, rem2 = rem % 4096;
        int n = rem2 >> 9, l = (rem2 >> 3) & 63, j = rem2 & 7;
        int k = ks * 32 + ((l >> 4) << 3) + j;
        int c = n * 16 + (l & 15);
        float v = (k < HD) ? W1[((size_t)r * HD + k) * MH + c] : 0.f;
        W1f[i] = f2bf(v);
    } else if (i < 114688 + 57344) {
        int t = i - 114688;
        int r = t / 14336, rem = t % 14336;
        int ks = rem / 3584, rem2 = rem % 3584;
        int n = rem2 >> 9, l = (rem2 >> 3) & 63, j = rem2 & 7;
        int k = ks * 32 + ((l >> 4) << 3) + j;
        int c = n * 16 + (l & 15);
        float v = (c < VD) ? W2[((size_t)r * MH + k) * VD + c] : 0.f;
        W2f[t] = f2bf(v);
    }
}

// ---------------- kernel 1: selection (fp64) + bucket compaction ----------------
// v6: h streamed with v3's proven linear 75-chunk walk (FETCH 42MB), 15-deep
// load batches; G delivered via CONSTANT-ADDRESS-SPACE scalar loads (s_load,
// K$-resident 12.8KB, SALU pipe) -- zero VMEM/DS traffic for G, VMEM path
// dedicated to the h-stream. Evidence: R7/R9 dur == hbm_bytes / 1TB/s (G
// delivery strangled memory-level parallelism); R8 proved hand-asm s_load
// serializes, so the as(4) path lets the COMPILER schedule the waits.
// Per-acc accumulation order identical to R9 -> bit-identical scores/argmax.
__global__ __launch_bounds__(256) void k1_select(
    const float* __restrict__ hidden, const double* __restrict__ Gc,
    int* __restrict__ cnt, unsigned short* __restrict__ list16,
    unsigned char* __restrict__ vbyte)
{
    __shared__ int lcnt[NR];
    __shared__ int lbase[NR];
    int tid = threadIdx.x;
    if (tid < NR) lcnt[tid] = 0;
    __syncthreads();

    gconst_t G4 = (gconst_t)(unsigned long long)Gc;

    int b = blockIdx.x * 256 + tid;
    const float4* h4 = (const float4*)(hidden + (size_t)b * 300);

    double acc[16];
#pragma unroll
    for (int c = 0; c < 16; ++c) acc[c] = 0.0;

    for (int c0 = 0; c0 < 75; c0 += 15) {
        float4 hv[15];
#pragma unroll
        for (int u = 0; u < 15; ++u) hv[u] = h4[c0 + u];
#pragma unroll
        for (int u = 0; u < 15; ++u) {
            int ch = c0 + u;              // compile-time within unrolled body
            int seg = ch / 25;            // 0: h[0], 1: h[1], 2: h[2]
            int cc = ch - seg * 25;
            float e[4] = {hv[u].x, hv[u].y, hv[u].z, hv[u].w};
#pragma unroll
            for (int q = 0; q < 4; ++q) {
                int dd = cc * 4 + q;
                double x = (double)e[q];
                if (seg == 0) {
#pragma unroll
                    for (int r = 0; r < 4; ++r)
                        acc[r] = fma(x, G4[dd * 16 + r], acc[r]);
                } else if (seg == 1) {
#pragma unroll
                    for (int r = 0; r < 4; ++r)
                        acc[4 + r] = fma(x, G4[dd * 16 + 4 + r], acc[4 + r]);
                } else {
#pragma unroll
                    for (int r = 0; r < 8; ++r)
                        acc[8 + r] = fma(x, G4[dd * 16 + 8 + r], acc[8 + r]);
                }
            }
        }
    }

    // scores p = r*2+v (reshape order); first-occurrence argmax
    double sc[8];
#pragma unroll
    for (int r = 0; r < 4; ++r) {
        sc[r * 2]     = acc[r]     + acc[8 + r];
        sc[r * 2 + 1] = acc[4 + r] + acc[12 + r];
    }
    int best = 0; double bv = sc[0];
#pragma unroll
    for (int p = 1; p < 8; ++p) if (sc[p] > bv) { bv = sc[p]; best = p; }
    int r = best >> 1, v = best & 1;

    vbyte[b] = (unsigned char)v;
    int pos = atomicAdd(&lcnt[r], 1);
    __syncthreads();
    if (tid < NR) lbase[tid] = atomicAdd(&cnt[tid], lcnt[tid]);
    __syncthreads();
    list16[r * B_TOTAL + lbase[r] + pos] = (unsigned short)b;
}

// ---------------- kernel 2: bucketed bf16-MFMA MLP ----------------
// v3 (proven R9: dropped out of top-5, ~15us): 64-row tiles, LDS 30KB,
// ~5 blocks/CU; 4 threads/row staging with 13 batched float4.
__global__ __launch_bounds__(256) void k2_mlp(
    const float* __restrict__ hidden,
    const unsigned short* __restrict__ W1f, const unsigned short* __restrict__ W2f,
    const int* __restrict__ cnt, const unsigned short* __restrict__ list16,
    const unsigned char* __restrict__ vbyte, float* __restrict__ out)
{
    int r = blockIdx.y;
    int nb = cnt[r];
    int m0 = blockIdx.x * 64;
    if (m0 >= nb) return;
    int me = nb - m0; if (me > 64) me = 64;

    __shared__ __align__(16) unsigned short shbuf[64 * 232]; // X [64][232]; C1 overlay [64][136]
    __shared__ int ent[64];

    int tid = threadIdx.x;
    int wave = tid >> 6, lane = tid & 63;
    int lr = lane & 15, lk = lane >> 4;
    int wrow0 = wave * 16;

    if (tid < 64) {
        int idx = m0 + tid; if (idx > nb - 1) idx = nb - 1;
        int b = list16[r * B_TOTAL + idx];
        int v = vbyte[b];
        ent[tid] = (b << 1) | v;
    }
    __syncthreads();

    // stage X: thread = (e, h, t): e=tid>>2 row, h=(tid>>1)&1 seg-half,
    // t=tid&1 sub-half. 13 consecutive float4 batched into regs.
    {
        int e = tid >> 2, hh = (tid >> 1) & 1, t = tid & 1;
        int en = ent[e];
        int b = en >> 1, v = en & 1;
        int seg = hh ? (1 - v) : v;
        int q0 = t * 12;   // 0..12 / 12..24 (chunk 12 written twice, same value)
        const float4* src = (const float4*)(hidden + (size_t)b * 300 + seg * 100) + q0;
        float4 hv[13];
#pragma unroll
        for (int u = 0; u < 13; ++u) hv[u] = src[u];
#pragma unroll
        for (int u = 0; u < 13; ++u) {
            ushort4 o;
            o.x = f2bf(hv[u].x); o.y = f2bf(hv[u].y);
            o.z = f2bf(hv[u].z); o.w = f2bf(hv[u].w);
            *(ushort4*)&shbuf[e * 232 + (hh * 25 + q0 + u) * 4] = o;
        }
    }
    // zero-pad k = [200,232) fully: 4 bf16x8 chunks per row (NaN-laundering
    // hazard: stale LDS * 0-weight = NaN -> relu -> zeroed rows).
    {
        int row = tid >> 2, part = tid & 3;
        bf16x8 z = {0, 0, 0, 0, 0, 0, 0, 0};
        *(bf16x8*)&shbuf[row * 232 + 200 + part * 8] = z;
    }
    __syncthreads();

    // ---- GEMM1 ----
    const unsigned short* W1f_r = W1f + (size_t)r * 28672;
    f32x4 acc1[8];
#pragma unroll
    for (int n = 0; n < 8; ++n) acc1[n] = (f32x4){0.f, 0.f, 0.f, 0.f};

#pragma unroll
    for (int ks = 0; ks < 7; ++ks) {
        bf16x8 a0 = *(const bf16x8*)&shbuf[(wrow0 + lr) * 232 + ks * 32 + lk * 8];
#pragma unroll
        for (int n = 0; n < 8; ++n) {
            bf16x8 bfr = *(const bf16x8*)&W1f_r[(size_t)(ks * 8 + n) * 512 + lane * 8];
            acc1[n] = __builtin_amdgcn_mfma_f32_16x16x32_bf16(a0, bfr, acc1[n], 0, 0, 0);
        }
    }

    __syncthreads();  // all waves done reading X before overlay

    // relu -> bf16 -> C1 transpose-store: row=wrow0+(lane>>4)*4+j, col=n*16+(lane&15)
#pragma unroll
    for (int n = 0; n < 8; ++n)
#pragma unroll
        for (int j = 0; j < 4; ++j) {
            float v = fmaxf(acc1[n][j], 0.f);
            int row = wrow0 + lk * 4 + j;
            shbuf[row * 136 + n * 16 + lr] = f2bf(v);
        }
    __syncthreads();

    // ---- GEMM2 ----
    const unsigned short* W2f_r = W2f + (size_t)r * 14336;
    f32x4 acc2[7];
#pragma unroll
    for (int n = 0; n < 7; ++n) acc2[n] = (f32x4){0.f, 0.f, 0.f, 0.f};

#pragma unroll
    for (int ks = 0; ks < 4; ++ks) {
        bf16x8 a0 = *(const bf16x8*)&shbuf[(wrow0 + lr) * 136 + ks * 32 + lk * 8];
#pragma unroll
        for (int n = 0; n < 7; ++n) {
            bf16x8 bfr = *(const bf16x8*)&W2f_r[(size_t)(ks * 7 + n) * 512 + lane * 8];
            acc2[n] = __builtin_amdgcn_mfma_f32_16x16x32_bf16(a0, bfr, acc2[n], 0, 0, 0);
        }
    }

    // scatter-store
#pragma unroll
    for (int n = 0; n < 7; ++n) {
        int col = n * 16 + lr;
        if (col < VD) {
#pragma unroll
            for (int j = 0; j < 4; ++j) {
                int e = wrow0 + lk * 4 + j;
                if (e < me) {
                    int b = ent[e] >> 1;
                    out[(size_t)b * VD + col] = acc2[n][j];
                }
            }
        }
    }
}

extern "C" void kernel_launch(void* const* d_in, const int* in_sizes, int n_in,
                              void* d_out, int out_size, void* d_ws, size_t ws_size,
                              hipStream_t stream) {
    (void)in_sizes; (void)n_in; (void)out_size; (void)ws_size;
    const float* hidden   = (const float*)d_in[0];
    const float* rule_emb = (const float*)d_in[1];
    const float* Wq       = (const float*)d_in[2];
    const float* bq       = (const float*)d_in[3];
    const float* Wk       = (const float*)d_in[4];
    const float* W1       = (const float*)d_in[5];
    const float* W2       = (const float*)d_in[6];
    float* out = (float*)d_out;

    char* ws = (char*)d_ws;
    double* Gc             = (double*)(ws + WS_GC);
    int* cnt               = (int*)(ws + WS_CNT);
    unsigned short* list16 = (unsigned short*)(ws + WS_LIST);
    unsigned char* vbyte   = (unsigned char*)(ws + WS_VB);
    unsigned short* W1f    = (unsigned short*)(ws + WS_W1F);
    unsigned short* W2f    = (unsigned short*)(ws + WS_W2F);

    k0_prep<<<1, 256, 0, stream>>>(rule_emb, Wq, bq, Wk, Gc, cnt);
    k0_wfrag<<<672, 256, 0, stream>>>(W1, W2, W1f, W2f);
    k1_select<<<256, 256, 0, stream>>>(hidden, Gc, cnt, list16, vbyte);
    k2_mlp<<<dim3(1024, NR), 256, 0, stream>>>(hidden, W1f, W2f, cnt, list16, vbyte, out);
}